// Round 1
// baseline (91.150 us; speedup 1.0000x reference)
//
#include <hip/hip_runtime.h>
#include <hip/hip_bf16.h>

// NT-Xent loss, B=4096, D=128, N=8192, T=0.5, EPS=1e-8.
// loss = mean_k [ log( sum_j exp(2*cos(k,j)) - e^2 ) - 2*cos(k, partner(k)) ]
// exp via exp2 with 2*log2(e) folded into the A-side bf16 cast.

#define NROWS 8192
#define BHALF 4096
#define DDIM  128
#define TM    128
#define TN    128
#define NSPLIT 8
#define TILES_PER_SPLIT ((NROWS / TN) / NSPLIT)   // 8
#define LDS_PAD 8
#define LDA (DDIM + LDS_PAD)                      // 136 bf16 elems -> 272 B row stride

#define SCALE_A 2.8853900817779268f   // 2 * log2(e)
#define E2F     7.38905609893065f     // e^2

typedef unsigned short u16;
typedef __attribute__((ext_vector_type(8))) short bf16x8;
typedef __attribute__((ext_vector_type(4))) float f32x4;

static __device__ inline u16 f2bf(float x) {
    __hip_bfloat16 h = __float2bfloat16(x);
    return *reinterpret_cast<u16*>(&h);
}

static __device__ inline float dev_exp2(float x) {
#if __has_builtin(__builtin_amdgcn_exp2f)
    return __builtin_amdgcn_exp2f(x);
#else
    return exp2f(x);
#endif
}

// ---------------------------------------------------------------------------
// Kernel 1: per-row norms, bf16 casts (znA scaled by 2*log2e, znB plain),
// fp32 pos[k], zero rowsum[k]. One wave per row.
// ---------------------------------------------------------------------------
__global__ __launch_bounds__(64) void prep_kernel(
    const float* __restrict__ zi, const float* __restrict__ zj,
    u16* __restrict__ znA, u16* __restrict__ znB,
    float* __restrict__ pos, float* __restrict__ rowsum)
{
    const int row  = blockIdx.x;          // 0..8191
    const int lane = threadIdx.x;         // 0..63

    const float* zk;
    const float* zp;
    if (row < BHALF) {
        zk = zi + (size_t)row * DDIM;
        zp = zj + (size_t)row * DDIM;     // partner = row + B  -> zj[row]
    } else {
        zk = zj + (size_t)(row - BHALF) * DDIM;
        zp = zi + (size_t)(row - BHALF) * DDIM;  // partner = row - B -> zi[row-B]
    }

    float2 a = *(const float2*)(zk + lane * 2);
    float2 b = *(const float2*)(zp + lane * 2);

    float ss = a.x * a.x + a.y * a.y;     // |z_k|^2 partial
    float sp = b.x * b.x + b.y * b.y;     // |z_p|^2 partial
    float dp = a.x * b.x + a.y * b.y;     // dot partial
    #pragma unroll
    for (int o = 32; o > 0; o >>= 1) {
        ss += __shfl_xor(ss, o);
        sp += __shfl_xor(sp, o);
        dp += __shfl_xor(dp, o);
    }

    float nk = fmaxf(sqrtf(ss), 1e-8f);
    float np = fmaxf(sqrtf(sp), 1e-8f);
    float invk = 1.0f / nk;

    // bf16 casts, packed as one u32 store per lane per array
    float sA = invk * SCALE_A;
    unsigned int pa = (unsigned int)f2bf(a.x * sA) |
                      ((unsigned int)f2bf(a.y * sA) << 16);
    unsigned int pb = (unsigned int)f2bf(a.x * invk) |
                      ((unsigned int)f2bf(a.y * invk) << 16);
    ((unsigned int*)znA)[row * (DDIM / 2) + lane] = pa;
    ((unsigned int*)znB)[row * (DDIM / 2) + lane] = pb;

    if (lane == 0) {
        pos[row] = 2.0f * dp * invk / np;
        rowsum[row] = 0.0f;
    }
}

// ---------------------------------------------------------------------------
// Kernel 2: tiled bf16 MFMA sim + exp2 + row-sum accumulation.
// Grid: (64 row-blocks, 8 col-splits). Block: 256 thr = 4 waves (2x2 wave grid).
// Each wave: 64x64 of the 128x128 tile = 4x4 frags of 16x16, K=128 in 4 steps.
// ---------------------------------------------------------------------------
__global__ __launch_bounds__(256, 2) void gemm_lse_kernel(
    const u16* __restrict__ znA, const u16* __restrict__ znB,
    float* __restrict__ rowsum)
{
    __shared__ __align__(16) u16 As[TM * LDA];
    __shared__ __align__(16) u16 Bs[TN * LDA];

    const int rb   = blockIdx.x;              // row block 0..63
    const int cs   = blockIdx.y;              // col split 0..7
    const int t    = threadIdx.x;
    const int wave = t >> 6;
    const int lane = t & 63;
    const int wr   = (wave >> 1) * 64;        // wave row offset in tile
    const int wc   = (wave & 1) * 64;         // wave col offset in tile
    const int l15  = lane & 15;
    const int l4   = lane >> 4;

    // --- stage A tile once (rows rb*128 .. +127, all K) ---
    {
        const u16* src = znA + (size_t)rb * TM * DDIM;
        #pragma unroll
        for (int i = 0; i < 8; ++i) {
            int c = t + i * 256;              // 16B chunk id, 0..2047
            int row = c >> 4;
            int col8 = (c & 15) * 8;
            uint4 v = *(const uint4*)(src + row * DDIM + col8);
            *(uint4*)(&As[row * LDA + col8]) = v;
        }
    }

    float psum[16];
    #pragma unroll
    for (int i = 0; i < 16; ++i) psum[i] = 0.0f;

    for (int ct = 0; ct < TILES_PER_SPLIT; ++ct) {
        const int colbase = (cs * TILES_PER_SPLIT + ct) * TN;

        __syncthreads();   // previous tile's reads done (also covers As writes)
        {
            const u16* src = znB + (size_t)colbase * DDIM;
            #pragma unroll
            for (int i = 0; i < 8; ++i) {
                int c = t + i * 256;
                int row = c >> 4;
                int col8 = (c & 15) * 8;
                uint4 v = *(const uint4*)(src + row * DDIM + col8);
                *(uint4*)(&Bs[row * LDA + col8]) = v;
            }
        }
        __syncthreads();

        f32x4 acc[4][4];
        #pragma unroll
        for (int r = 0; r < 4; ++r)
            #pragma unroll
            for (int c = 0; c < 4; ++c)
                acc[r][c] = (f32x4){0.0f, 0.0f, 0.0f, 0.0f};

        #pragma unroll
        for (int ks = 0; ks < 4; ++ks) {
            bf16x8 af[4], bfr[4];
            #pragma unroll
            for (int r = 0; r < 4; ++r)
                af[r] = *(const bf16x8*)(&As[(wr + r * 16 + l15) * LDA + ks * 32 + l4 * 8]);
            #pragma unroll
            for (int c = 0; c < 4; ++c)
                bfr[c] = *(const bf16x8*)(&Bs[(wc + c * 16 + l15) * LDA + ks * 32 + l4 * 8]);
            #pragma unroll
            for (int r = 0; r < 4; ++r)
                #pragma unroll
                for (int c = 0; c < 4; ++c)
                    acc[r][c] = __builtin_amdgcn_mfma_f32_16x16x32_bf16(
                        af[r], bfr[c], acc[r][c], 0, 0, 0);
        }

        // epilogue: exp2 each sim value, accumulate per-lane row partials.
        // C layout: col = l15 (per frag), row = r*16 + l4*4 + i.
        #pragma unroll
        for (int r = 0; r < 4; ++r) {
            #pragma unroll
            for (int i = 0; i < 4; ++i) {
                float s = dev_exp2(acc[r][0][i]) + dev_exp2(acc[r][1][i])
                        + dev_exp2(acc[r][2][i]) + dev_exp2(acc[r][3][i]);
                psum[r * 4 + i] += s;
            }
        }
    }

    // reduce across the 16 column-lanes of each quad group
    #pragma unroll
    for (int i = 0; i < 16; ++i) {
        float v = psum[i];
        v += __shfl_xor(v, 1);
        v += __shfl_xor(v, 2);
        v += __shfl_xor(v, 4);
        v += __shfl_xor(v, 8);
        psum[i] = v;
    }

    if (l15 == 0) {
        #pragma unroll
        for (int r = 0; r < 4; ++r)
            #pragma unroll
            for (int i = 0; i < 4; ++i)
                atomicAdd(&rowsum[rb * TM + wr + r * 16 + l4 * 4 + i],
                          psum[r * 4 + i]);
    }
}

// ---------------------------------------------------------------------------
// Kernel 3: loss = mean( log(rowsum - e^2) - pos )
// ---------------------------------------------------------------------------
__global__ __launch_bounds__(256) void final_kernel(
    const float* __restrict__ rowsum, const float* __restrict__ pos,
    float* __restrict__ out)
{
    __shared__ float red[256];
    const int t = threadIdx.x;
    float s = 0.0f;
    for (int k = t; k < NROWS; k += 256)
        s += logf(rowsum[k] - E2F) - pos[k];
    red[t] = s;
    __syncthreads();
    for (int w = 128; w > 0; w >>= 1) {
        if (t < w) red[t] += red[t + w];
        __syncthreads();
    }
    if (t == 0) out[0] = red[0] / (float)NROWS;
}

// ---------------------------------------------------------------------------
extern "C" void kernel_launch(void* const* d_in, const int* in_sizes, int n_in,
                              void* d_out, int out_size, void* d_ws, size_t ws_size,
                              hipStream_t stream)
{
    const float* zi = (const float*)d_in[0];
    const float* zj = (const float*)d_in[1];
    float* out = (float*)d_out;

    char* ws = (char*)d_ws;
    u16*   znA    = (u16*)(ws);                          // 8192*128*2 = 2 MB
    u16*   znB    = (u16*)(ws + (2u << 20));             // 2 MB
    float* rowsum = (float*)(ws + (4u << 20));           // 32 KB
    float* pos    = (float*)(ws + (4u << 20) + 32768);   // 32 KB

    prep_kernel<<<NROWS, 64, 0, stream>>>(zi, zj, znA, znB, pos, rowsum);
    gemm_lse_kernel<<<dim3(NROWS / TM, NSPLIT), 256, 0, stream>>>(znA, znB, rowsum);
    final_kernel<<<1, 256, 0, stream>>>(rowsum, pos, out);
}

// Round 2
// 80.450 us; speedup vs baseline: 1.1330x; 1.1330x over previous
//
#include <hip/hip_runtime.h>
#include <hip/hip_bf16.h>

// NT-Xent loss, B=4096, D=128, N=8192, T=0.5, EPS=1e-8.
// loss = mean_k [ log( sum_j exp(2*cos(k,j)) - e^2 ) - 2*cos(k, partner(k)) ]
// Round 2: no-LDS, no-barrier GEMM with MX-fp8 K=128 MFMA, frags direct from
// global in a tile-transposed layout. exp via exp2 with 2*log2(e) folded into
// the A-side fp8 cast.

#define NROWS 8192
#define BHALF 4096
#define DDIM  128

#define SCALE_A 2.8853900817779268f   // 2 * log2(e)
#define E2F     7.38905609893065f     // e^2
#define LN2F    0.6931471805599453f

typedef unsigned short u16;
typedef unsigned char  u8;
typedef __attribute__((ext_vector_type(8))) int   i32x8;
typedef __attribute__((ext_vector_type(4))) float f32x4;

static __device__ inline float dev_exp2(float x) {
#if __has_builtin(__builtin_amdgcn_exp2f)
    return __builtin_amdgcn_exp2f(x);
#else
    return exp2f(x);
#endif
}

static __device__ inline float dev_log2(float x) {
#if __has_builtin(__builtin_amdgcn_logf)
    return __builtin_amdgcn_logf(x);
#else
    return log2f(x);
#endif
}

#if !__has_builtin(__builtin_amdgcn_cvt_pk_fp8_f32)
#include <hip/hip_fp8.h>
#endif

// pack two floats to two OCP e4m3 bytes (low 16 bits)
static __device__ inline u16 pk_fp8(float x, float y) {
#if __has_builtin(__builtin_amdgcn_cvt_pk_fp8_f32)
    int v = __builtin_amdgcn_cvt_pk_fp8_f32(x, y, 0, false);
    return (u16)(v & 0xffff);
#else
    __hip_fp8_e4m3 a(x), b(y);
    return (u16)(a.__x | ((u16)b.__x << 8));
#endif
}

static __device__ inline i32x8 mk8(uint4 lo, uint4 hi) {
    i32x8 v;
    v[0] = (int)lo.x; v[1] = (int)lo.y; v[2] = (int)lo.z; v[3] = (int)lo.w;
    v[4] = (int)hi.x; v[5] = (int)hi.y; v[6] = (int)hi.z; v[7] = (int)hi.w;
    return v;
}

// ---------------------------------------------------------------------------
// zn_t layout: row r -> group g = r>>4, rr = r&15. 16B chunk c (elements
// k in [16c,16c+16)) stored at byte offset g*2048 + c*256 + rr*16.
// A 16-lane MFMA fragment load (rows = l15, k-chunk fixed) is then a fully
// coalesced 256B run, and operand bytes land in plain k order per lane-quad.
// ---------------------------------------------------------------------------

// Kernel 1: norms, fp8 casts into tile-transposed layout (znA scaled by
// 2*log2e, znB unit), fp32 pos[k], zero rowsum[k]. One wave per row.
__global__ __launch_bounds__(256) void prep_kernel(
    const float* __restrict__ zi, const float* __restrict__ zj,
    u8* __restrict__ znA, u8* __restrict__ znB,
    float* __restrict__ pos, float* __restrict__ rowsum)
{
    const int row  = blockIdx.x * 4 + (threadIdx.x >> 6);
    const int lane = threadIdx.x & 63;

    const float* zk;
    const float* zp;
    if (row < BHALF) {
        zk = zi + (size_t)row * DDIM;
        zp = zj + (size_t)row * DDIM;            // partner = row + B
    } else {
        zk = zj + (size_t)(row - BHALF) * DDIM;
        zp = zi + (size_t)(row - BHALF) * DDIM;  // partner = row - B
    }

    float2 a = *(const float2*)(zk + lane * 2);
    float2 b = *(const float2*)(zp + lane * 2);

    float ss = a.x * a.x + a.y * a.y;
    float sp = b.x * b.x + b.y * b.y;
    float dp = a.x * b.x + a.y * b.y;
    #pragma unroll
    for (int o = 32; o > 0; o >>= 1) {
        ss += __shfl_xor(ss, o);
        sp += __shfl_xor(sp, o);
        dp += __shfl_xor(dp, o);
    }

    float nk   = fmaxf(sqrtf(ss), 1e-8f);
    float np   = fmaxf(sqrtf(sp), 1e-8f);
    float invk = 1.0f / nk;
    float sA   = invk * SCALE_A;

    // elements k = 2*lane, 2*lane+1
    const int g  = row >> 4;
    const int rr = row & 15;
    const int addr = g * 2048 + ((lane >> 3) << 8) + (rr << 4) + ((lane & 7) << 1);

    *(u16*)(znA + addr) = pk_fp8(a.x * sA,   a.y * sA);
    *(u16*)(znB + addr) = pk_fp8(a.x * invk, a.y * invk);

    if (lane == 0) {
        pos[row]    = 2.0f * dp * invk / np;
        rowsum[row] = 0.0f;
    }
}

// ---------------------------------------------------------------------------
// Kernel 2: no-LDS MFMA sim + exp2 + row-sum. Grid (128, 4) x 256 threads.
// Each wave: 64 rows x 512 cols (8 tiles of 64 cols), K=128 in one
// mfma_scale_f32_16x16x128_f8f6f4 per 16x16 output frag. No __syncthreads.
// ---------------------------------------------------------------------------
__global__ __launch_bounds__(256, 2) void gemm_lse_kernel(
    const u8* __restrict__ znA, const u8* __restrict__ znB,
    float* __restrict__ rowsum)
{
    const int wave = threadIdx.x >> 6;
    const int lane = threadIdx.x & 63;
    const int l15  = lane & 15;
    const int l4   = lane >> 4;

    const int rowbase = blockIdx.x * 64;                 // 128 row-blocks
    const int colbase = (blockIdx.y * 4 + wave) * 512;   // 16 col-splits

    const int laneoff = (l4 * 2) * 256 + l15 * 16;       // chunk 2*l4, row l15

    // --- A fragments, loaded once, reused across 8 tiles ---
    i32x8 a[4];
    #pragma unroll
    for (int r = 0; r < 4; ++r) {
        const u8* p = znA + (size_t)((rowbase >> 4) + r) * 2048 + laneoff;
        uint4 lo = *(const uint4*)(p);
        uint4 hi = *(const uint4*)(p + 256);
        a[r] = mk8(lo, hi);
    }

    float psum[16];
    #pragma unroll
    for (int i = 0; i < 16; ++i) psum[i] = 0.0f;

    const f32x4 zero = {0.0f, 0.0f, 0.0f, 0.0f};

    // --- B prefetch for tile 0 ---
    i32x8 bcur[4], bnxt[4];
    #pragma unroll
    for (int c = 0; c < 4; ++c) {
        const u8* p = znB + (size_t)((colbase >> 4) + c) * 2048 + laneoff;
        uint4 lo = *(const uint4*)(p);
        uint4 hi = *(const uint4*)(p + 256);
        bcur[c] = mk8(lo, hi);
    }

    #pragma unroll
    for (int ct = 0; ct < 8; ++ct) {
        // prefetch next tile's B frags (in flight during MFMA + epilogue)
        if (ct < 7) {
            #pragma unroll
            for (int c = 0; c < 4; ++c) {
                const u8* p = znB + (size_t)((colbase >> 4) + (ct + 1) * 4 + c) * 2048 + laneoff;
                uint4 lo = *(const uint4*)(p);
                uint4 hi = *(const uint4*)(p + 256);
                bnxt[c] = mk8(lo, hi);
            }
        }

        #pragma unroll
        for (int r = 0; r < 4; ++r) {
            f32x4 t0 = __builtin_amdgcn_mfma_scale_f32_16x16x128_f8f6f4(
                a[r], bcur[0], zero, 0, 0, 0, 0x7f7f7f7f, 0, 0x7f7f7f7f);
            f32x4 t1 = __builtin_amdgcn_mfma_scale_f32_16x16x128_f8f6f4(
                a[r], bcur[1], zero, 0, 0, 0, 0x7f7f7f7f, 0, 0x7f7f7f7f);
            f32x4 t2 = __builtin_amdgcn_mfma_scale_f32_16x16x128_f8f6f4(
                a[r], bcur[2], zero, 0, 0, 0, 0x7f7f7f7f, 0, 0x7f7f7f7f);
            f32x4 t3 = __builtin_amdgcn_mfma_scale_f32_16x16x128_f8f6f4(
                a[r], bcur[3], zero, 0, 0, 0, 0x7f7f7f7f, 0, 0x7f7f7f7f);
            #pragma unroll
            for (int i = 0; i < 4; ++i) {
                psum[r * 4 + i] += dev_exp2(t0[i]) + dev_exp2(t1[i])
                                 + dev_exp2(t2[i]) + dev_exp2(t3[i]);
            }
        }

        #pragma unroll
        for (int c = 0; c < 4; ++c) bcur[c] = bnxt[c];
    }

    // reduce across the 16 column-lanes (l15) of each quad group
    #pragma unroll
    for (int i = 0; i < 16; ++i) {
        float v = psum[i];
        v += __shfl_xor(v, 1);
        v += __shfl_xor(v, 2);
        v += __shfl_xor(v, 4);
        v += __shfl_xor(v, 8);
        psum[i] = v;
    }

    if (l15 == 0) {
        #pragma unroll
        for (int r = 0; r < 4; ++r)
            #pragma unroll
            for (int i = 0; i < 4; ++i)
                atomicAdd(&rowsum[rowbase + r * 16 + l4 * 4 + i],
                          psum[r * 4 + i]);
    }
}

// ---------------------------------------------------------------------------
// Kernel 3: loss = mean( log(rowsum - e^2) - pos )
// ---------------------------------------------------------------------------
__global__ __launch_bounds__(256) void final_kernel(
    const float* __restrict__ rowsum, const float* __restrict__ pos,
    float* __restrict__ out)
{
    const int t = threadIdx.x;
    float s = 0.0f;
    #pragma unroll
    for (int k = t; k < NROWS; k += 256)
        s += dev_log2(rowsum[k] - E2F) * LN2F - pos[k];

    #pragma unroll
    for (int o = 32; o > 0; o >>= 1) s += __shfl_xor(s, o);

    __shared__ float red[4];
    if ((t & 63) == 0) red[t >> 6] = s;
    __syncthreads();
    if (t == 0) out[0] = (red[0] + red[1] + red[2] + red[3]) * (1.0f / (float)NROWS);
}

// ---------------------------------------------------------------------------
extern "C" void kernel_launch(void* const* d_in, const int* in_sizes, int n_in,
                              void* d_out, int out_size, void* d_ws, size_t ws_size,
                              hipStream_t stream)
{
    const float* zi = (const float*)d_in[0];
    const float* zj = (const float*)d_in[1];
    float* out = (float*)d_out;

    char* ws = (char*)d_ws;
    u8*    znA    = (u8*)(ws);                           // 8192*128 = 1 MB
    u8*    znB    = (u8*)(ws + (1u << 20));              // 1 MB
    float* rowsum = (float*)(ws + (2u << 20));           // 32 KB
    float* pos    = (float*)(ws + (2u << 20) + 32768);   // 32 KB

    prep_kernel<<<NROWS / 4, 256, 0, stream>>>(zi, zj, znA, znB, pos, rowsum);
    gemm_lse_kernel<<<dim3(128, 4), 256, 0, stream>>>(znA, znB, rowsum);
    final_kernel<<<1, 256, 0, stream>>>(rowsum, pos, out);
}